// Round 26
// baseline (180.171 us; speedup 1.0000x reference)
//
#include <hip/hip_runtime.h>

typedef __bf16 bf16;
typedef __attribute__((ext_vector_type(8))) __bf16 bf16x8;
typedef __attribute__((ext_vector_type(4))) __bf16 bf16x4;
typedef __attribute__((ext_vector_type(4))) float f32x4;

constexpr int T_SEQ = 2048;
constexpr int DIM   = 2048;
constexpr int NH    = 32;
constexpr int NKV   = 8;
constexpr int HD    = 64;
constexpr int QKV_N = DIM + 2 * NKV * HD;   // 3072
constexpr int MROWS = 2 * T_SEQ;            // 4096 (B*T)

// ---------------- fused cast: x -> xb, wq|wk|wv -> wqkv, wo -> wob ----------------
__global__ void cast_all_kernel(const float* __restrict__ x,
                                const float* __restrict__ wq, const float* __restrict__ wk,
                                const float* __restrict__ wv, const float* __restrict__ wo,
                                bf16* __restrict__ xb, bf16* __restrict__ wqkv,
                                bf16* __restrict__ wob) {
  int stride = gridDim.x * blockDim.x;
  for (int g = blockIdx.x * blockDim.x + threadIdx.x; g < 4718592; g += stride) {
    const float* src; bf16* dst; int off;
    if (g < 2097152)      { src = x;  dst = xb;             off = g; }
    else if (g < 3145728) { src = wq; dst = wqkv;           off = g - 2097152; }
    else if (g < 3407872) { src = wk; dst = wqkv + 4194304; off = g - 3145728; }
    else if (g < 3670016) { src = wv; dst = wqkv + 5242880; off = g - 3407872; }
    else                  { src = wo; dst = wob;            off = g - 3670016; }
    float4 v = *(const float4*)(src + (size_t)off * 4);
    bf16x4 o = { (bf16)v.x, (bf16)v.y, (bf16)v.z, (bf16)v.w };
    *(bf16x4*)(dst + (size_t)off * 4) = o;
  }
}

// rect XCD decode for 256-block 16x16 grids: XCD c gets an 8(bm) x 4(bn) rect.
__device__ inline void rect_decode(int orig, int& bmi, int& bni) {
  int c = orig & 7, i = orig >> 3;
  bmi = (c & 1) * 8 + (i & 7);
  bni = (c >> 1) * 4 + (i >> 3);
}

// ---------------- out-proj GEMM: BM=256 BN=128, A ring-3, vmcnt(6) ----------------
__global__ __launch_bounds__(512) void gemm256(const bf16* __restrict__ A,
                                               const bf16* __restrict__ W,
                                               float* __restrict__ C,
                                               int N, int K) {
  constexpr int BM = 256, BN = 128, BK = 64;
  __shared__ __attribute__((aligned(16))) bf16 Ab[3][BM * BK];
  __shared__ __attribute__((aligned(16))) bf16 Bb[3][BN * BK];
  const int tid = threadIdx.x, lane = tid & 63, wave = tid >> 6;
  const int l15 = lane & 15, l4 = lane >> 4;
  int bmi, bni;
  rect_decode(blockIdx.x, bmi, bni);
  const int bm = bmi * BM, bn = bni * BN;
  const int wm = (wave >> 1) * 64, wn = (wave & 1) * 64;

  f32x4 acc[4][4] = {};

  const int NT = K / BK;
  auto stage = [&](int s, int k0) {
    #pragma unroll
    for (int i = 0; i < 4; ++i) {
      int c = i * 512 + tid;
      int row = c >> 3;
      int gc = ((c & 7) ^ (row & 7)) << 3;
      __builtin_amdgcn_global_load_lds(
          (const __attribute__((address_space(1))) unsigned int*)(A + (size_t)(bm + row) * K + k0 + gc),
          (__attribute__((address_space(3))) unsigned int*)(&Ab[s][0] + c * 8), 16, 0, 0);
    }
    #pragma unroll
    for (int i = 0; i < 2; ++i) {
      int c = i * 512 + tid;
      int row = c >> 3;
      int gc = ((c & 7) ^ (row & 7)) << 3;
      __builtin_amdgcn_global_load_lds(
          (const __attribute__((address_space(1))) unsigned int*)(W + (size_t)(bn + row) * K + k0 + gc),
          (__attribute__((address_space(3))) unsigned int*)(&Bb[s][0] + c * 8), 16, 0, 0);
    }
  };

  stage(0, 0);
  stage(1, BK);

  int d = 0;
  for (int t = 0; t < NT; ++t) {
    if (t + 1 < NT) { asm volatile("s_waitcnt vmcnt(6)" ::: "memory"); }
    else            { asm volatile("s_waitcnt vmcnt(0)" ::: "memory"); }
    __builtin_amdgcn_s_barrier();

    bf16x8 af[2][4], bfr[2][4];
    #pragma unroll
    for (int kk = 0; kk < 2; ++kk) {
      #pragma unroll
      for (int mi = 0; mi < 4; ++mi) {
        int row = wm + mi * 16 + l15;
        af[kk][mi] = *(const bf16x8*)((const char*)&Ab[d][0] + row * 128 +
                                      (((kk * 4 + l4) ^ (row & 7)) << 4));
      }
      #pragma unroll
      for (int ni = 0; ni < 4; ++ni) {
        int row = wn + ni * 16 + l15;
        bfr[kk][ni] = *(const bf16x8*)((const char*)&Bb[d][0] + row * 128 +
                                       (((kk * 4 + l4) ^ (row & 7)) << 4));
      }
    }

    if (t + 2 < NT) {
      int s = d + 2; if (s >= 3) s -= 3;
      stage(s, (t + 2) * BK);
    }

    __builtin_amdgcn_s_setprio(1);
    #pragma unroll
    for (int kk = 0; kk < 2; ++kk)
      #pragma unroll
      for (int mi = 0; mi < 4; ++mi)
        #pragma unroll
        for (int ni = 0; ni < 4; ++ni)
          acc[mi][ni] = __builtin_amdgcn_mfma_f32_16x16x32_bf16(af[kk][mi], bfr[kk][ni],
                                                                acc[mi][ni], 0, 0, 0);
    __builtin_amdgcn_s_setprio(0);

    ++d; if (d == 3) d = 0;
  }

  #pragma unroll
  for (int mi = 0; mi < 4; ++mi)
    #pragma unroll
    for (int ni = 0; ni < 4; ++ni) {
      size_t row = (size_t)bm + wm + mi * 16 + l4 * 4;
      int col = bn + wn + ni * 16 + l15;
      #pragma unroll
      for (int r = 0; r < 4; ++r)
        C[(row + r) * N + col] = acc[mi][ni][r];
    }
}

// ---------------- QKV GEMM: BM=256 BN=192 + fused RoPE (R20) ----------------
__global__ __launch_bounds__(512, 1) void gemm192(const bf16* __restrict__ A,
                                                  const bf16* __restrict__ W,
                                                  bf16* __restrict__ C,
                                                  const float* __restrict__ cs,
                                                  const float* __restrict__ sn) {
  constexpr int BM = 256, BN = 192, BK = 64, N = QKV_N, K = DIM;
  __shared__ __attribute__((aligned(16))) bf16 Ab[3][BM * BK];
  __shared__ __attribute__((aligned(16))) bf16 Bb[2][BN * BK];
  const int tid = threadIdx.x, lane = tid & 63, wave = tid >> 6;
  const int l15 = lane & 15, l4 = lane >> 4;
  int bmi, bni;
  rect_decode(blockIdx.x, bmi, bni);
  const int bm = bmi * BM, bn = bni * BN;
  const int wm = (wave >> 1) * 64, wn = (wave & 1) * 96;

  f32x4 acc[4][6] = {};

  constexpr int NT = K / BK;   // 32
  auto stageA = [&](int s, int k0) {
    #pragma unroll
    for (int i = 0; i < 4; ++i) {
      int c = i * 512 + tid;
      int row = c >> 3;
      int gc = ((c & 7) ^ (row & 7)) << 3;
      __builtin_amdgcn_global_load_lds(
          (const __attribute__((address_space(1))) unsigned int*)(A + (size_t)(bm + row) * K + k0 + gc),
          (__attribute__((address_space(3))) unsigned int*)(&Ab[s][0] + c * 8), 16, 0, 0);
    }
  };
  auto stageB = [&](int s, int k0) {
    #pragma unroll
    for (int i = 0; i < 3; ++i) {
      int c = i * 512 + tid;
      int row = c >> 3;
      int gc = ((c & 7) ^ (row & 7)) << 3;
      __builtin_amdgcn_global_load_lds(
          (const __attribute__((address_space(1))) unsigned int*)(W + (size_t)(bn + row) * K + k0 + gc),
          (__attribute__((address_space(3))) unsigned int*)(&Bb[s][0] + c * 8), 16, 0, 0);
    }
  };

  stageA(0, 0);
  stageB(0, 0);
  stageA(1, BK);

  for (int t = 0; t < NT; ++t) {
    const int d3 = t % 3, db = t & 1;
    if (t + 1 < NT) { asm volatile("s_waitcnt vmcnt(4)" ::: "memory"); }
    else            { asm volatile("s_waitcnt vmcnt(0)" ::: "memory"); }
    __builtin_amdgcn_s_barrier();

    bf16x8 af[2][4], bfr[2][6];
    #pragma unroll
    for (int kk = 0; kk < 2; ++kk) {
      #pragma unroll
      for (int mi = 0; mi < 4; ++mi) {
        int row = wm + mi * 16 + l15;
        af[kk][mi] = *(const bf16x8*)((const char*)&Ab[d3][0] + row * 128 +
                                      (((kk * 4 + l4) ^ (row & 7)) << 4));
      }
      #pragma unroll
      for (int ni = 0; ni < 6; ++ni) {
        int row = wn + ni * 16 + l15;
        bfr[kk][ni] = *(const bf16x8*)((const char*)&Bb[db][0] + row * 128 +
                                       (((kk * 4 + l4) ^ (row & 7)) << 4));
      }
    }

    if (t + 1 < NT) stageB(db ^ 1, (t + 1) * BK);
    if (t + 2 < NT) { int s = d3 + 2; if (s >= 3) s -= 3; stageA(s, (t + 2) * BK); }

    __builtin_amdgcn_s_setprio(1);
    #pragma unroll
    for (int kk = 0; kk < 2; ++kk)
      #pragma unroll
      for (int mi = 0; mi < 4; ++mi)
        #pragma unroll
        for (int ni = 0; ni < 6; ++ni)
          acc[mi][ni] = __builtin_amdgcn_mfma_f32_16x16x32_bf16(af[kk][mi], bfr[kk][ni],
                                                                acc[mi][ni], 0, 0, 0);
    __builtin_amdgcn_s_setprio(0);
  }

  const bool odd = (l15 & 1);
  #pragma unroll
  for (int ni = 0; ni < 6; ++ni) {
    if (bn + wn + ni * 16 < 2560) {
      int col = bn + wn + ni * 16 + l15;
      int ip = (col & 63) >> 1;
      #pragma unroll
      for (int mi = 0; mi < 4; ++mi) {
        int row0 = wm + mi * 16 + l4 * 4;
        #pragma unroll
        for (int r = 0; r < 4; ++r) {
          int tpos = (bm + row0 + r) & (T_SEQ - 1);
          float c = cs[tpos * 32 + ip];
          float s = sn[tpos * 32 + ip];
          float a = acc[mi][ni][r];
          float p = __shfl_xor(a, 1);
          acc[mi][ni][r] = odd ? (p * s + a * c) : (a * c - p * s);
        }
      }
    }
  }

  #pragma unroll
  for (int mi = 0; mi < 4; ++mi)
    #pragma unroll
    for (int ni = 0; ni < 6; ++ni) {
      size_t row = (size_t)bm + wm + mi * 16 + l4 * 4;
      int col = bn + wn + ni * 16 + l15;
      #pragma unroll
      for (int r = 0; r < 4; ++r)
        C[(row + r) * N + col] = (bf16)acc[mi][ni][r];
    }
}

// ---------------- Flash attention, causal GQA, 2 heads/block ----------------
// grid (NH/2, 16, B); heads (2hp, 2hp+1) share kv head g = hp>>1 -> K/V
// staging and every kf/vf LDS read serve BOTH heads (2 MFMAs per read).
// LDS unchanged 80KB -> 2 blocks/CU. Same KVBLK=128, Kb/VTs dbuf, 1 barrier/
// tile, T5 setprio, ones-MFMA l, max3-tree, defer-max. Pb reused A-then-B.
__global__ __launch_bounds__(512, 2) void attn_kernel(const bf16* __restrict__ qkv,
                                                      bf16* __restrict__ y) {
  const int hp = blockIdx.x, b = blockIdx.z;
  const int strip = 15 - blockIdx.y;
  const int h0 = 2 * hp, g = hp >> 1;
  const int tid = threadIdx.x, lane = tid & 63, wave = tid >> 6;
  const int l15 = lane & 15, l4 = lane >> 4;
  const int qbase = strip * 128 + wave * 16;

  __shared__ __attribute__((aligned(16))) bf16 Kb[2][128 * 64];
  __shared__ __attribute__((aligned(16))) bf16 VTs[2][2][64 * 64];
  __shared__ __attribute__((aligned(16))) bf16 Pb[8][16 * 64];

  constexpr float SCALE2 = 0.125f * 1.44269504088896f;
  constexpr float THR_RAW = 8.0f / SCALE2;
  constexpr int VOFF = DIM + NKV * HD;

  const bf16 one1 = (bf16)1.0f;
  const bf16x8 ones = { one1, one1, one1, one1, one1, one1, one1, one1 };

  bf16x8 qfA[2], qfB[2];
  {
    const bf16* qp = qkv + ((size_t)b * T_SEQ + qbase + l15) * QKV_N + h0 * HD + l4 * 8;
    qfA[0] = *(const bf16x8*)(qp);
    qfA[1] = *(const bf16x8*)(qp + 32);
    qfB[0] = *(const bf16x8*)(qp + HD);
    qfB[1] = *(const bf16x8*)(qp + HD + 32);
  }

  f32x4 oaccA[4] = {}, oaccB[4] = {};
  f32x4 laccA = {}, laccB = {};
  float mA = -INFINITY, mB = -INFINITY;
  const int qg = qbase + l15;

  const int nt = strip + 1;
  const size_t kvbase = (size_t)b * T_SEQ;
  const int vwoff = ((lane * 128 + wave * 16) ^ ((lane & 7) << 4));

  {
    #pragma unroll
    for (int i = 0; i < 2; ++i) {
      int chunk = i * 512 + tid;
      int row = chunk >> 3;
      int csrc = ((chunk & 7) << 3) ^ ((row & 7) << 3);
      __builtin_amdgcn_global_load_lds(
          (const __attribute__((address_space(1))) unsigned int*)
              (qkv + (kvbase + row) * QKV_N + DIM + g * HD + csrc),
          (__attribute__((address_space(3))) unsigned int*)(&Kb[0][0] + chunk * 8), 16, 0, 0);
    }
    #pragma unroll
    for (int hf = 0; hf < 2; ++hf) {
      const bf16* vp = qkv + (kvbase + hf * 64 + wave * 8) * QKV_N + VOFF + g * HD + lane;
      bf16x8 vr;
      #pragma unroll
      for (int j = 0; j < 8; ++j) vr[j] = vp[(size_t)j * QKV_N];
      *(bf16x8*)((char*)&VTs[0][hf][0] + vwoff) = vr;
    }
    asm volatile("s_waitcnt vmcnt(0)" ::: "memory");
    __syncthreads();
  }

  int cur = 0;
  for (int kt = 0; kt < nt; ++kt) {
    const bool has_next = (kt + 1) < nt;
    bf16x8 vr0, vr1;
    if (has_next) {
      #pragma unroll
      for (int i = 0; i < 2; ++i) {
        int chunk = i * 512 + tid;
        int row = chunk >> 3;
        int csrc = ((chunk & 7) << 3) ^ ((row & 7) << 3);
        __builtin_amdgcn_global_load_lds(
            (const __attribute__((address_space(1))) unsigned int*)
                (qkv + (kvbase + (kt + 1) * 128 + row) * QKV_N + DIM + g * HD + csrc),
            (__attribute__((address_space(3))) unsigned int*)(&Kb[cur ^ 1][0] + chunk * 8), 16, 0, 0);
      }
      const bf16* vp0 = qkv + (kvbase + (kt + 1) * 128 + wave * 8) * QKV_N + VOFF + g * HD + lane;
      const bf16* vp1 = vp0 + (size_t)64 * QKV_N;
      #pragma unroll
      for (int j = 0; j < 8; ++j) vr0[j] = vp0[(size_t)j * QKV_N];
      #pragma unroll
      for (int j = 0; j < 8; ++j) vr1[j] = vp1[(size_t)j * QKV_N];
    }

    const bf16* kb = &Kb[cur][0];
    const bool diag = (kt == strip);

    #pragma unroll
    for (int hf = 0; hf < 2; ++hf) {
      if (diag && hf == 1 && wave < 4) continue;

      // ---- QK^T both heads, kf shared ----
      f32x4 zA[4], zB[4];
      #pragma unroll
      for (int nt4 = 0; nt4 < 4; ++nt4) {
        zA[nt4] = (f32x4){0.f, 0.f, 0.f, 0.f};
        zB[nt4] = (f32x4){0.f, 0.f, 0.f, 0.f};
      }
      __builtin_amdgcn_s_setprio(1);
      #pragma unroll
      for (int nt4 = 0; nt4 < 4; ++nt4)
        #pragma unroll
        for (int kk = 0; kk < 2; ++kk) {
          bf16x8 kf = *(const bf16x8*)((const char*)kb +
              (((hf * 64 + nt4 * 16 + l15) * 128 + (kk * 32 + l4 * 8) * 2) ^ ((l15 & 7) << 4)));
          zA[nt4] = __builtin_amdgcn_mfma_f32_16x16x32_bf16(kf, qfA[kk], zA[nt4], 0, 0, 0);
          zB[nt4] = __builtin_amdgcn_mfma_f32_16x16x32_bf16(kf, qfB[kk], zB[nt4], 0, 0, 0);
        }
      __builtin_amdgcn_s_setprio(0);

      if (diag) {
        #pragma unroll
        for (int nt4 = 0; nt4 < 4; ++nt4)
          #pragma unroll
          for (int r = 0; r < 4; ++r)
            if (kt * 128 + hf * 64 + nt4 * 16 + l4 * 4 + r > qg) {
              zA[nt4][r] = -INFINITY;
              zB[nt4][r] = -INFINITY;
            }
      }

      bf16* pbw = &Pb[wave][0];
      bf16x8 pfA[2], pfB[2];

      // ---- softmax + P stage, head A ----
      {
        float a0 = fmaxf(fmaxf(zA[0][0], zA[0][1]), zA[0][2]);
        float a1 = fmaxf(fmaxf(zA[0][3], zA[1][0]), zA[1][1]);
        float a2 = fmaxf(fmaxf(zA[1][2], zA[1][3]), zA[2][0]);
        float a3 = fmaxf(fmaxf(zA[2][1], zA[2][2]), zA[2][3]);
        float a4 = fmaxf(fmaxf(zA[3][0], zA[3][1]), zA[3][2]);
        float vm = fmaxf(fmaxf(fmaxf(a0, a1), a2), fmaxf(fmaxf(a3, a4), zA[3][3]));
        vm = fmaxf(vm, __shfl_xor(vm, 16));
        vm = fmaxf(vm, __shfl_xor(vm, 32));
        if (!__all(vm - mA <= THR_RAW)) {
          float mnew = fmaxf(mA, vm);
          float alpha = __builtin_amdgcn_exp2f((mA - mnew) * SCALE2);
          #pragma unroll
          for (int r = 0; r < 4; ++r) laccA[r] *= alpha;
          #pragma unroll
          for (int dt = 0; dt < 4; ++dt)
            #pragma unroll
            for (int r = 0; r < 4; ++r) oaccA[dt][r] *= alpha;
          mA = mnew;
        }
        const float ms = mA * SCALE2;
        #pragma unroll
        for (int nt4 = 0; nt4 < 4; ++nt4)
          #pragma unroll
          for (int r = 0; r < 4; ++r)
            zA[nt4][r] = __builtin_amdgcn_exp2f(__builtin_fmaf(zA[nt4][r], SCALE2, -ms));
        #pragma unroll
        for (int nt4 = 0; nt4 < 4; ++nt4) {
          bf16x4 pk = { (bf16)zA[nt4][0], (bf16)zA[nt4][1], (bf16)zA[nt4][2], (bf16)zA[nt4][3] };
          *(bf16x4*)((char*)pbw + ((l15 * 128 + nt4 * 32 + l4 * 8) ^ ((l15 & 7) << 4))) = pk;
        }
        #pragma unroll
        for (int kk = 0; kk < 2; ++kk)
          pfA[kk] = *(const bf16x8*)((const char*)pbw +
              ((l15 * 128 + kk * 64 + l4 * 16) ^ ((l15 & 7) << 4)));
      }

      // ---- softmax + P stage, head B ----
      {
        float a0 = fmaxf(fmaxf(zB[0][0], zB[0][1]), zB[0][2]);
        float a1 = fmaxf(fmaxf(zB[0][3], zB[1][0]), zB[1][1]);
        float a2 = fmaxf(fmaxf(zB[1][2], zB[1][3]), zB[2][0]);
        float a3 = fmaxf(fmaxf(zB[2][1], zB[2][2]), zB[2][3]);
        float a4 = fmaxf(fmaxf(zB[3][0], zB[3][1]), zB[3][2]);
        float vm = fmaxf(fmaxf(fmaxf(a0, a1), a2), fmaxf(fmaxf(a3, a4), zB[3][3]));
        vm = fmaxf(vm, __shfl_xor(vm, 16));
        vm = fmaxf(vm, __shfl_xor(vm, 32));
        if (!__all(vm - mB <= THR_RAW)) {
          float mnew = fmaxf(mB, vm);
          float alpha = __builtin_amdgcn_exp2f((mB - mnew) * SCALE2);
          #pragma unroll
          for (int r = 0; r < 4; ++r) laccB[r] *= alpha;
          #pragma unroll
          for (int dt = 0; dt < 4; ++dt)
            #pragma unroll
            for (int r = 0; r < 4; ++r) oaccB[dt][r] *= alpha;
          mB = mnew;
        }
        const float ms = mB * SCALE2;
        #pragma unroll
        for (int nt4 = 0; nt4 < 4; ++nt4)
          #pragma unroll
          for (int r = 0; r < 4; ++r)
            zB[nt4][r] = __builtin_amdgcn_exp2f(__builtin_fmaf(zB[nt4][r], SCALE2, -ms));
        #pragma unroll
        for (int nt4 = 0; nt4 < 4; ++nt4) {
          bf16x4 pk = { (bf16)zB[nt4][0], (bf16)zB[nt4][1], (bf16)zB[nt4][2], (bf16)zB[nt4][3] };
          *(bf16x4*)((char*)pbw + ((l15 * 128 + nt4 * 32 + l4 * 8) ^ ((l15 & 7) << 4))) = pk;
        }
        #pragma unroll
        for (int kk = 0; kk < 2; ++kk)
          pfB[kk] = *(const bf16x8*)((const char*)pbw +
              ((l15 * 128 + kk * 64 + l4 * 16) ^ ((l15 & 7) << 4)));
      }

      // ---- PV both heads, vf shared ----
      const bf16* vt = &VTs[cur][hf][0];
      __builtin_amdgcn_s_setprio(1);
      #pragma unroll
      for (int kk = 0; kk < 2; ++kk) {
        laccA = __builtin_amdgcn_mfma_f32_16x16x32_bf16(ones, pfA[kk], laccA, 0, 0, 0);
        laccB = __builtin_amdgcn_mfma_f32_16x16x32_bf16(ones, pfB[kk], laccB, 0, 0, 0);
        #pragma unroll
        for (int dt = 0; dt < 4; ++dt) {
          bf16x8 vf = *(const bf16x8*)((const char*)vt +
              (((dt * 16 + l15) * 128 + (kk * 32 + l4 * 8) * 2) ^ ((l15 & 7) << 4)));
          oaccA[dt] = __builtin_amdgcn_mfma_f32_16x16x32_bf16(vf, pfA[kk], oaccA[dt], 0, 0, 0);
          oaccB[dt] = __builtin_amdgcn_mfma_f32_16x16x32_bf16(vf, pfB[kk], oaccB[dt], 0, 0, 0);
        }
      }
      __builtin_amdgcn_s_setprio(0);
    }

    if (has_next) {
      *(bf16x8*)((char*)&VTs[cur ^ 1][0][0] + vwoff) = vr0;
      *(bf16x8*)((char*)&VTs[cur ^ 1][1][0] + vwoff) = vr1;
      __syncthreads();
      cur ^= 1;
    }
  }

  // ---- epilogue: both heads ----
  {
    float linvA = __builtin_amdgcn_rcpf(laccA[0]);
    float linvB = __builtin_amdgcn_rcpf(laccB[0]);
    bf16* yp = y + ((size_t)b * T_SEQ + qbase + l15) * DIM + h0 * HD + l4 * 4;
    #pragma unroll
    for (int dt = 0; dt < 4; ++dt) {
      bf16x4 ovA = { (bf16)(oaccA[dt][0] * linvA), (bf16)(oaccA[dt][1] * linvA),
                     (bf16)(oaccA[dt][2] * linvA), (bf16)(oaccA[dt][3] * linvA) };
      bf16x4 ovB = { (bf16)(oaccB[dt][0] * linvB), (bf16)(oaccB[dt][1] * linvB),
                     (bf16)(oaccB[dt][2] * linvB), (bf16)(oaccB[dt][3] * linvB) };
      *(bf16x4*)(yp + dt * 16) = ovA;
      *(bf16x4*)(yp + HD + dt * 16) = ovB;
    }
  }
}

// ---------------- launch ----------------
extern "C" void kernel_launch(void* const* d_in, const int* in_sizes, int n_in,
                              void* d_out, int out_size, void* d_ws, size_t ws_size,
                              hipStream_t stream) {
  const float* x    = (const float*)d_in[0];
  const float* cosb = (const float*)d_in[1];
  const float* sinb = (const float*)d_in[2];
  const float* wq   = (const float*)d_in[3];
  const float* wk   = (const float*)d_in[4];
  const float* wv   = (const float*)d_in[5];
  const float* wo   = (const float*)d_in[6];
  float* out = (float*)d_out;

  bf16* xb   = (bf16*)d_ws;                           // 4096*2048
  bf16* wqkv = xb + (size_t)MROWS * DIM;              // 3072*2048
  bf16* wob  = wqkv + (size_t)QKV_N * DIM;            // 2048*2048
  bf16* qkv  = wob + (size_t)DIM * DIM;               // 4096*3072
  bf16* y    = qkv + (size_t)MROWS * QKV_N;           // 4096*2048

  // fused casts (one launch)
  cast_all_kernel<<<2048, 256, 0, stream>>>(x, wq, wk, wv, wo, xb, wqkv, wob);

  // QKV projection + fused RoPE: BM=256 BN=192 -> 256 blocks, one round
  gemm192<<<256, 512, 0, stream>>>(xb, wqkv, qkv, cosb, sinb);

  // attention: 2 heads/block (shared K/V), 512 blocks = exact residency fill
  attn_kernel<<<dim3(NH / 2, 16, 2), 512, 0, stream>>>(qkv, y);

  // output projection: BM=256 BN=128 -> 256 blocks, one round
  gemm256<<<256, 512, 0, stream>>>(y, wob, out, DIM, DIM);
}

// Round 27
// 160.599 us; speedup vs baseline: 1.1219x; 1.1219x over previous
//
#include <hip/hip_runtime.h>

typedef __bf16 bf16;
typedef __attribute__((ext_vector_type(8))) __bf16 bf16x8;
typedef __attribute__((ext_vector_type(4))) __bf16 bf16x4;
typedef __attribute__((ext_vector_type(4))) float f32x4;

constexpr int T_SEQ = 2048;
constexpr int DIM   = 2048;
constexpr int NH    = 32;
constexpr int NKV   = 8;
constexpr int HD    = 64;
constexpr int QKV_N = DIM + 2 * NKV * HD;   // 3072
constexpr int MROWS = 2 * T_SEQ;            // 4096 (B*T)

// ---------------- fused cast: x -> xb, wq|wk|wv -> wqkv, wo -> wob ----------------
__global__ void cast_all_kernel(const float* __restrict__ x,
                                const float* __restrict__ wq, const float* __restrict__ wk,
                                const float* __restrict__ wv, const float* __restrict__ wo,
                                bf16* __restrict__ xb, bf16* __restrict__ wqkv,
                                bf16* __restrict__ wob) {
  int stride = gridDim.x * blockDim.x;
  for (int g = blockIdx.x * blockDim.x + threadIdx.x; g < 4718592; g += stride) {
    const float* src; bf16* dst; int off;
    if (g < 2097152)      { src = x;  dst = xb;             off = g; }
    else if (g < 3145728) { src = wq; dst = wqkv;           off = g - 2097152; }
    else if (g < 3407872) { src = wk; dst = wqkv + 4194304; off = g - 3145728; }
    else if (g < 3670016) { src = wv; dst = wqkv + 5242880; off = g - 3407872; }
    else                  { src = wo; dst = wob;            off = g - 3670016; }
    float4 v = *(const float4*)(src + (size_t)off * 4);
    bf16x4 o = { (bf16)v.x, (bf16)v.y, (bf16)v.z, (bf16)v.w };
    *(bf16x4*)(dst + (size_t)off * 4) = o;
  }
}

// rect XCD decode for 256-block 16x16 grids: XCD c gets an 8(bm) x 4(bn) rect.
__device__ inline void rect_decode(int orig, int& bmi, int& bni) {
  int c = orig & 7, i = orig >> 3;
  bmi = (c & 1) * 8 + (i & 7);
  bni = (c >> 1) * 4 + (i >> 3);
}

// ---------------- out-proj GEMM: BM=256 BN=128, A ring-3, vmcnt(6) ----------------
__global__ __launch_bounds__(512) void gemm256(const bf16* __restrict__ A,
                                               const bf16* __restrict__ W,
                                               float* __restrict__ C,
                                               int N, int K) {
  constexpr int BM = 256, BN = 128, BK = 64;
  __shared__ __attribute__((aligned(16))) bf16 Ab[3][BM * BK];
  __shared__ __attribute__((aligned(16))) bf16 Bb[3][BN * BK];
  const int tid = threadIdx.x, lane = tid & 63, wave = tid >> 6;
  const int l15 = lane & 15, l4 = lane >> 4;
  int bmi, bni;
  rect_decode(blockIdx.x, bmi, bni);
  const int bm = bmi * BM, bn = bni * BN;
  const int wm = (wave >> 1) * 64, wn = (wave & 1) * 64;

  f32x4 acc[4][4] = {};

  const int NT = K / BK;
  auto stage = [&](int s, int k0) {
    #pragma unroll
    for (int i = 0; i < 4; ++i) {
      int c = i * 512 + tid;
      int row = c >> 3;
      int gc = ((c & 7) ^ (row & 7)) << 3;
      __builtin_amdgcn_global_load_lds(
          (const __attribute__((address_space(1))) unsigned int*)(A + (size_t)(bm + row) * K + k0 + gc),
          (__attribute__((address_space(3))) unsigned int*)(&Ab[s][0] + c * 8), 16, 0, 0);
    }
    #pragma unroll
    for (int i = 0; i < 2; ++i) {
      int c = i * 512 + tid;
      int row = c >> 3;
      int gc = ((c & 7) ^ (row & 7)) << 3;
      __builtin_amdgcn_global_load_lds(
          (const __attribute__((address_space(1))) unsigned int*)(W + (size_t)(bn + row) * K + k0 + gc),
          (__attribute__((address_space(3))) unsigned int*)(&Bb[s][0] + c * 8), 16, 0, 0);
    }
  };

  stage(0, 0);
  stage(1, BK);

  int d = 0;
  for (int t = 0; t < NT; ++t) {
    if (t + 1 < NT) { asm volatile("s_waitcnt vmcnt(6)" ::: "memory"); }
    else            { asm volatile("s_waitcnt vmcnt(0)" ::: "memory"); }
    __builtin_amdgcn_s_barrier();

    bf16x8 af[2][4], bfr[2][4];
    #pragma unroll
    for (int kk = 0; kk < 2; ++kk) {
      #pragma unroll
      for (int mi = 0; mi < 4; ++mi) {
        int row = wm + mi * 16 + l15;
        af[kk][mi] = *(const bf16x8*)((const char*)&Ab[d][0] + row * 128 +
                                      (((kk * 4 + l4) ^ (row & 7)) << 4));
      }
      #pragma unroll
      for (int ni = 0; ni < 4; ++ni) {
        int row = wn + ni * 16 + l15;
        bfr[kk][ni] = *(const bf16x8*)((const char*)&Bb[d][0] + row * 128 +
                                       (((kk * 4 + l4) ^ (row & 7)) << 4));
      }
    }

    if (t + 2 < NT) {
      int s = d + 2; if (s >= 3) s -= 3;
      stage(s, (t + 2) * BK);
    }

    __builtin_amdgcn_s_setprio(1);
    #pragma unroll
    for (int kk = 0; kk < 2; ++kk)
      #pragma unroll
      for (int mi = 0; mi < 4; ++mi)
        #pragma unroll
        for (int ni = 0; ni < 4; ++ni)
          acc[mi][ni] = __builtin_amdgcn_mfma_f32_16x16x32_bf16(af[kk][mi], bfr[kk][ni],
                                                                acc[mi][ni], 0, 0, 0);
    __builtin_amdgcn_s_setprio(0);

    ++d; if (d == 3) d = 0;
  }

  #pragma unroll
  for (int mi = 0; mi < 4; ++mi)
    #pragma unroll
    for (int ni = 0; ni < 4; ++ni) {
      size_t row = (size_t)bm + wm + mi * 16 + l4 * 4;
      int col = bn + wn + ni * 16 + l15;
      #pragma unroll
      for (int r = 0; r < 4; ++r)
        C[(row + r) * N + col] = acc[mi][ni][r];
    }
}

// ---------------- QKV GEMM: BM=256 BN=192 + fused RoPE (R20) ----------------
__global__ __launch_bounds__(512, 1) void gemm192(const bf16* __restrict__ A,
                                                  const bf16* __restrict__ W,
                                                  bf16* __restrict__ C,
                                                  const float* __restrict__ cs,
                                                  const float* __restrict__ sn) {
  constexpr int BM = 256, BN = 192, BK = 64, N = QKV_N, K = DIM;
  __shared__ __attribute__((aligned(16))) bf16 Ab[3][BM * BK];
  __shared__ __attribute__((aligned(16))) bf16 Bb[2][BN * BK];
  const int tid = threadIdx.x, lane = tid & 63, wave = tid >> 6;
  const int l15 = lane & 15, l4 = lane >> 4;
  int bmi, bni;
  rect_decode(blockIdx.x, bmi, bni);
  const int bm = bmi * BM, bn = bni * BN;
  const int wm = (wave >> 1) * 64, wn = (wave & 1) * 96;

  f32x4 acc[4][6] = {};

  constexpr int NT = K / BK;   // 32
  auto stageA = [&](int s, int k0) {
    #pragma unroll
    for (int i = 0; i < 4; ++i) {
      int c = i * 512 + tid;
      int row = c >> 3;
      int gc = ((c & 7) ^ (row & 7)) << 3;
      __builtin_amdgcn_global_load_lds(
          (const __attribute__((address_space(1))) unsigned int*)(A + (size_t)(bm + row) * K + k0 + gc),
          (__attribute__((address_space(3))) unsigned int*)(&Ab[s][0] + c * 8), 16, 0, 0);
    }
  };
  auto stageB = [&](int s, int k0) {
    #pragma unroll
    for (int i = 0; i < 3; ++i) {
      int c = i * 512 + tid;
      int row = c >> 3;
      int gc = ((c & 7) ^ (row & 7)) << 3;
      __builtin_amdgcn_global_load_lds(
          (const __attribute__((address_space(1))) unsigned int*)(W + (size_t)(bn + row) * K + k0 + gc),
          (__attribute__((address_space(3))) unsigned int*)(&Bb[s][0] + c * 8), 16, 0, 0);
    }
  };

  stageA(0, 0);
  stageB(0, 0);
  stageA(1, BK);

  for (int t = 0; t < NT; ++t) {
    const int d3 = t % 3, db = t & 1;
    if (t + 1 < NT) { asm volatile("s_waitcnt vmcnt(4)" ::: "memory"); }
    else            { asm volatile("s_waitcnt vmcnt(0)" ::: "memory"); }
    __builtin_amdgcn_s_barrier();

    bf16x8 af[2][4], bfr[2][6];
    #pragma unroll
    for (int kk = 0; kk < 2; ++kk) {
      #pragma unroll
      for (int mi = 0; mi < 4; ++mi) {
        int row = wm + mi * 16 + l15;
        af[kk][mi] = *(const bf16x8*)((const char*)&Ab[d3][0] + row * 128 +
                                      (((kk * 4 + l4) ^ (row & 7)) << 4));
      }
      #pragma unroll
      for (int ni = 0; ni < 6; ++ni) {
        int row = wn + ni * 16 + l15;
        bfr[kk][ni] = *(const bf16x8*)((const char*)&Bb[db][0] + row * 128 +
                                       (((kk * 4 + l4) ^ (row & 7)) << 4));
      }
    }

    if (t + 1 < NT) stageB(db ^ 1, (t + 1) * BK);
    if (t + 2 < NT) { int s = d3 + 2; if (s >= 3) s -= 3; stageA(s, (t + 2) * BK); }

    __builtin_amdgcn_s_setprio(1);
    #pragma unroll
    for (int kk = 0; kk < 2; ++kk)
      #pragma unroll
      for (int mi = 0; mi < 4; ++mi)
        #pragma unroll
        for (int ni = 0; ni < 6; ++ni)
          acc[mi][ni] = __builtin_amdgcn_mfma_f32_16x16x32_bf16(af[kk][mi], bfr[kk][ni],
                                                                acc[mi][ni], 0, 0, 0);
    __builtin_amdgcn_s_setprio(0);
  }

  const bool odd = (l15 & 1);
  #pragma unroll
  for (int ni = 0; ni < 6; ++ni) {
    if (bn + wn + ni * 16 < 2560) {
      int col = bn + wn + ni * 16 + l15;
      int ip = (col & 63) >> 1;
      #pragma unroll
      for (int mi = 0; mi < 4; ++mi) {
        int row0 = wm + mi * 16 + l4 * 4;
        #pragma unroll
        for (int r = 0; r < 4; ++r) {
          int tpos = (bm + row0 + r) & (T_SEQ - 1);
          float c = cs[tpos * 32 + ip];
          float s = sn[tpos * 32 + ip];
          float a = acc[mi][ni][r];
          float p = __shfl_xor(a, 1);
          acc[mi][ni][r] = odd ? (p * s + a * c) : (a * c - p * s);
        }
      }
    }
  }

  #pragma unroll
  for (int mi = 0; mi < 4; ++mi)
    #pragma unroll
    for (int ni = 0; ni < 6; ++ni) {
      size_t row = (size_t)bm + wm + mi * 16 + l4 * 4;
      int col = bn + wn + ni * 16 + l15;
      #pragma unroll
      for (int r = 0; r < 4; ++r)
        C[(row + r) * N + col] = (bf16)acc[mi][ni][r];
    }
}

// ---------------- Flash attention, causal GQA (R25 best: R22 + T5 setprio) ----------------
// grid (NH, 16, B); 512 thr = 8 waves x 16 q-rows = ONE 128-row strip/block.
// KVBLK=128, Kb dbuf (glds) + VTs dbuf (reg-gather write-late) -> ONE barrier
// per 128-kv tile. LDS 80KB -> 2 blocks/CU. l via ones-MFMA; max3-tree max;
// defer-max; s_setprio(1) around QK^T and PV MFMA clusters (T5).
__global__ __launch_bounds__(512, 2) void attn_kernel(const bf16* __restrict__ qkv,
                                                      bf16* __restrict__ y) {
  const int h = blockIdx.x, b = blockIdx.z;
  const int strip = 15 - blockIdx.y;
  const int g = h >> 2;
  const int tid = threadIdx.x, lane = tid & 63, wave = tid >> 6;
  const int l15 = lane & 15, l4 = lane >> 4;
  const int qbase = strip * 128 + wave * 16;

  __shared__ __attribute__((aligned(16))) bf16 Kb[2][128 * 64];
  __shared__ __attribute__((aligned(16))) bf16 VTs[2][2][64 * 64];
  __shared__ __attribute__((aligned(16))) bf16 Pb[8][16 * 64];

  constexpr float SCALE2 = 0.125f * 1.44269504088896f;
  constexpr float THR_RAW = 8.0f / SCALE2;
  constexpr int VOFF = DIM + NKV * HD;

  const bf16 one1 = (bf16)1.0f;
  const bf16x8 ones = { one1, one1, one1, one1, one1, one1, one1, one1 };

  bf16x8 qf[2];
  {
    const bf16* qp = qkv + ((size_t)b * T_SEQ + qbase + l15) * QKV_N + h * HD + l4 * 8;
    qf[0] = *(const bf16x8*)(qp);
    qf[1] = *(const bf16x8*)(qp + 32);
  }

  f32x4 oacc[4] = {};
  f32x4 lacc = {};
  float m_run = -INFINITY;
  const int qg = qbase + l15;

  const int nt = strip + 1;
  const size_t kvbase = (size_t)b * T_SEQ;
  const int vwoff = ((lane * 128 + wave * 16) ^ ((lane & 7) << 4));

  {
    #pragma unroll
    for (int i = 0; i < 2; ++i) {
      int chunk = i * 512 + tid;
      int row = chunk >> 3;
      int csrc = ((chunk & 7) << 3) ^ ((row & 7) << 3);
      __builtin_amdgcn_global_load_lds(
          (const __attribute__((address_space(1))) unsigned int*)
              (qkv + (kvbase + row) * QKV_N + DIM + g * HD + csrc),
          (__attribute__((address_space(3))) unsigned int*)(&Kb[0][0] + chunk * 8), 16, 0, 0);
    }
    #pragma unroll
    for (int hf = 0; hf < 2; ++hf) {
      const bf16* vp = qkv + (kvbase + hf * 64 + wave * 8) * QKV_N + VOFF + g * HD + lane;
      bf16x8 vr;
      #pragma unroll
      for (int j = 0; j < 8; ++j) vr[j] = vp[(size_t)j * QKV_N];
      *(bf16x8*)((char*)&VTs[0][hf][0] + vwoff) = vr;
    }
    asm volatile("s_waitcnt vmcnt(0)" ::: "memory");
    __syncthreads();
  }

  int cur = 0;
  for (int kt = 0; kt < nt; ++kt) {
    const bool has_next = (kt + 1) < nt;
    bf16x8 vr0, vr1;
    if (has_next) {
      #pragma unroll
      for (int i = 0; i < 2; ++i) {
        int chunk = i * 512 + tid;
        int row = chunk >> 3;
        int csrc = ((chunk & 7) << 3) ^ ((row & 7) << 3);
        __builtin_amdgcn_global_load_lds(
            (const __attribute__((address_space(1))) unsigned int*)
                (qkv + (kvbase + (kt + 1) * 128 + row) * QKV_N + DIM + g * HD + csrc),
            (__attribute__((address_space(3))) unsigned int*)(&Kb[cur ^ 1][0] + chunk * 8), 16, 0, 0);
      }
      const bf16* vp0 = qkv + (kvbase + (kt + 1) * 128 + wave * 8) * QKV_N + VOFF + g * HD + lane;
      const bf16* vp1 = vp0 + (size_t)64 * QKV_N;
      #pragma unroll
      for (int j = 0; j < 8; ++j) vr0[j] = vp0[(size_t)j * QKV_N];
      #pragma unroll
      for (int j = 0; j < 8; ++j) vr1[j] = vp1[(size_t)j * QKV_N];
    }

    const bf16* kb = &Kb[cur][0];
    const bool diag = (kt == strip);

    #pragma unroll
    for (int hf = 0; hf < 2; ++hf) {
      if (diag && hf == 1 && wave < 4) continue;

      f32x4 z[4];
      #pragma unroll
      for (int nt4 = 0; nt4 < 4; ++nt4) z[nt4] = (f32x4){0.f, 0.f, 0.f, 0.f};
      __builtin_amdgcn_s_setprio(1);
      #pragma unroll
      for (int nt4 = 0; nt4 < 4; ++nt4)
        #pragma unroll
        for (int kk = 0; kk < 2; ++kk) {
          bf16x8 kf = *(const bf16x8*)((const char*)kb +
              (((hf * 64 + nt4 * 16 + l15) * 128 + (kk * 32 + l4 * 8) * 2) ^ ((l15 & 7) << 4)));
          z[nt4] = __builtin_amdgcn_mfma_f32_16x16x32_bf16(kf, qf[kk], z[nt4], 0, 0, 0);
        }
      __builtin_amdgcn_s_setprio(0);

      if (diag) {
        #pragma unroll
        for (int nt4 = 0; nt4 < 4; ++nt4)
          #pragma unroll
          for (int r = 0; r < 4; ++r)
            if (kt * 128 + hf * 64 + nt4 * 16 + l4 * 4 + r > qg) z[nt4][r] = -INFINITY;
      }

      float a0 = fmaxf(fmaxf(z[0][0], z[0][1]), z[0][2]);
      float a1 = fmaxf(fmaxf(z[0][3], z[1][0]), z[1][1]);
      float a2 = fmaxf(fmaxf(z[1][2], z[1][3]), z[2][0]);
      float a3 = fmaxf(fmaxf(z[2][1], z[2][2]), z[2][3]);
      float a4 = fmaxf(fmaxf(z[3][0], z[3][1]), z[3][2]);
      float b0 = fmaxf(fmaxf(a0, a1), a2);
      float b1 = fmaxf(fmaxf(a3, a4), z[3][3]);
      float vm = fmaxf(b0, b1);
      vm = fmaxf(vm, __shfl_xor(vm, 16));
      vm = fmaxf(vm, __shfl_xor(vm, 32));

      if (!__all(vm - m_run <= THR_RAW)) {
        float mnew = fmaxf(m_run, vm);
        float alpha = __builtin_amdgcn_exp2f((m_run - mnew) * SCALE2);
        #pragma unroll
        for (int r = 0; r < 4; ++r) lacc[r] *= alpha;
        #pragma unroll
        for (int dt = 0; dt < 4; ++dt)
          #pragma unroll
          for (int r = 0; r < 4; ++r) oacc[dt][r] *= alpha;
        m_run = mnew;
      }
      const float ms = m_run * SCALE2;

      #pragma unroll
      for (int nt4 = 0; nt4 < 4; ++nt4)
        #pragma unroll
        for (int r = 0; r < 4; ++r)
          z[nt4][r] = __builtin_amdgcn_exp2f(__builtin_fmaf(z[nt4][r], SCALE2, -ms));

      bf16* pbw = &Pb[wave][0];
      #pragma unroll
      for (int nt4 = 0; nt4 < 4; ++nt4) {
        bf16x4 pk = { (bf16)z[nt4][0], (bf16)z[nt4][1], (bf16)z[nt4][2], (bf16)z[nt4][3] };
        *(bf16x4*)((char*)pbw + ((l15 * 128 + nt4 * 32 + l4 * 8) ^ ((l15 & 7) << 4))) = pk;
      }

      const bf16* vt = &VTs[cur][hf][0];
      __builtin_amdgcn_s_setprio(1);
      #pragma unroll
      for (int kk = 0; kk < 2; ++kk) {
        bf16x8 pf = *(const bf16x8*)((const char*)pbw +
            ((l15 * 128 + kk * 64 + l4 * 16) ^ ((l15 & 7) << 4)));
        lacc = __builtin_amdgcn_mfma_f32_16x16x32_bf16(ones, pf, lacc, 0, 0, 0);
        #pragma unroll
        for (int dt = 0; dt < 4; ++dt) {
          bf16x8 vf = *(const bf16x8*)((const char*)vt +
              (((dt * 16 + l15) * 128 + (kk * 32 + l4 * 8) * 2) ^ ((l15 & 7) << 4)));
          oacc[dt] = __builtin_amdgcn_mfma_f32_16x16x32_bf16(vf, pf, oacc[dt], 0, 0, 0);
        }
      }
      __builtin_amdgcn_s_setprio(0);
    }

    if (has_next) {
      *(bf16x8*)((char*)&VTs[cur ^ 1][0][0] + vwoff) = vr0;
      *(bf16x8*)((char*)&VTs[cur ^ 1][1][0] + vwoff) = vr1;
      __syncthreads();
      cur ^= 1;
    }
  }

  {
    float linv = __builtin_amdgcn_rcpf(lacc[0]);
    bf16* yp = y + ((size_t)b * T_SEQ + qbase + l15) * DIM + h * HD + l4 * 4;
    #pragma unroll
    for (int dt = 0; dt < 4; ++dt) {
      bf16x4 ov = { (bf16)(oacc[dt][0] * linv), (bf16)(oacc[dt][1] * linv),
                    (bf16)(oacc[dt][2] * linv), (bf16)(oacc[dt][3] * linv) };
      *(bf16x4*)(yp + dt * 16) = ov;
    }
  }
}

// ---------------- launch ----------------
extern "C" void kernel_launch(void* const* d_in, const int* in_sizes, int n_in,
                              void* d_out, int out_size, void* d_ws, size_t ws_size,
                              hipStream_t stream) {
  const float* x    = (const float*)d_in[0];
  const float* cosb = (const float*)d_in[1];
  const float* sinb = (const float*)d_in[2];
  const float* wq   = (const float*)d_in[3];
  const float* wk   = (const float*)d_in[4];
  const float* wv   = (const float*)d_in[5];
  const float* wo   = (const float*)d_in[6];
  float* out = (float*)d_out;

  bf16* xb   = (bf16*)d_ws;                           // 4096*2048
  bf16* wqkv = xb + (size_t)MROWS * DIM;              // 3072*2048
  bf16* wob  = wqkv + (size_t)QKV_N * DIM;            // 2048*2048
  bf16* qkv  = wob + (size_t)DIM * DIM;               // 4096*3072
  bf16* y    = qkv + (size_t)MROWS * QKV_N;           // 4096*2048

  // fused casts (one launch)
  cast_all_kernel<<<2048, 256, 0, stream>>>(x, wq, wk, wv, wo, xb, wqkv, wob);

  // QKV projection + fused RoPE: BM=256 BN=192 -> 256 blocks, one round
  gemm192<<<256, 512, 0, stream>>>(xb, wqkv, qkv, cosb, sinb);

  // attention: R25 best (R22 structure + T5 setprio)
  attn_kernel<<<dim3(NH, 16, 2), 512, 0, stream>>>(qkv, y);

  // output projection: BM=256 BN=128 -> 256 blocks, one round
  gemm256<<<256, 512, 0, stream>>>(y, wob, out, DIM, DIM);
}